// Round 9
// baseline (124.222 us; speedup 1.0000x reference)
//
#include <hip/hip_runtime.h>

typedef __attribute__((ext_vector_type(8)))  short bf16x8;
typedef __attribute__((ext_vector_type(4)))  short s16x4;
typedef __attribute__((ext_vector_type(4)))  float f32x4;
typedef __attribute__((ext_vector_type(16))) float f32x16;
typedef __attribute__((ext_vector_type(4)))  unsigned u32x4;
typedef __attribute__((ext_vector_type(4)))  _Float16 f16x4;

#define B_  2
#define S_  2048
#define H_  16
#define D_  64
#define E_  1024
#define M_  (B_*S_)
#define NH_ (M_*H_)
#define L2E 1.44269504f

__device__ __forceinline__ unsigned short f2bf(float f){
  unsigned x = __builtin_bit_cast(unsigned, f);
  x += 0x7fffu + ((x >> 16) & 1u);
  return (unsigned short)(x >> 16);
}
__device__ __forceinline__ unsigned pk_bf16(float lo, float hi){
  unsigned short a = __builtin_bit_cast(unsigned short, (__bf16)lo);
  unsigned short b = __builtin_bit_cast(unsigned short, (__bf16)hi);
  return (unsigned)a | ((unsigned)b << 16);
}

#define GLD16(gp, lp) __builtin_amdgcn_global_load_lds( \
    (const __attribute__((address_space(1))) unsigned*)(gp), \
    (__attribute__((address_space(3))) unsigned*)(lp), 16, 0, 0)

// ---------------- x fp32 -> bf16, fused RoPE table + log2-mask build ----------------
__global__ __launch_bounds__(256) void k_cvt(const float* __restrict__ in, short* __restrict__ out,
                                             const float* __restrict__ mask,
                                             float* ct, float* st, float* maskC){
  int i = blockIdx.x*256 + threadIdx.x;
  if(i < S_*32){                           // RoPE tables [2048][32]
    int s = i >> 5, f = i & 31;
    float invf = powf(10000.0f, -(float)f / 32.0f);
    float ph = (float)s * invf;
    ct[i] = cosf(ph);
    st[i] = sinf(ph);
    if(i < B_*S_) maskC[i] = fmaf(mask[i], L2E, -17.0f);   // log2-domain mask, -17 recenter
  }
  int j = i*4;
  float4 v = *(const float4*)(in + j);
  s16x4 o = { (short)f2bf(v.x), (short)f2bf(v.y), (short)f2bf(v.z), (short)f2bf(v.w) };
  *(s16x4*)(out + j) = o;
}

// ---------------- W (K x N) fp32 -> W^T (N x K) bf16, 3 weights ----------------
__global__ __launch_bounds__(256) void k_wt(const float* __restrict__ Wq, const float* __restrict__ Wk,
                                            const float* __restrict__ Wv, short* __restrict__ wt){
  const float* W = blockIdx.z==0 ? Wq : (blockIdx.z==1 ? Wk : Wv);
  short* out = wt + (size_t)blockIdx.z*E_*E_;
  __shared__ short tile[64][72];
  int nb = blockIdx.x*64, kb = blockIdx.y*64;
  int t = threadIdx.x;
  {
    int r = t>>2, c0 = (t&3)*16;
    const float* src = W + (size_t)(kb+r)*E_ + nb + c0;
    #pragma unroll
    for(int i=0;i<4;i++){
      float4 v = *(const float4*)(src + i*4);
      tile[r][c0+i*4+0] = (short)f2bf(v.x);
      tile[r][c0+i*4+1] = (short)f2bf(v.y);
      tile[r][c0+i*4+2] = (short)f2bf(v.z);
      tile[r][c0+i*4+3] = (short)f2bf(v.w);
    }
  }
  __syncthreads();
  {
    int n = t>>2, k0 = (t&3)*16;
    short* dst = out + (size_t)(nb+n)*E_ + kb + k0;
    bf16x8 o0, o1;
    #pragma unroll
    for(int i=0;i<8;i++){ o0[i] = tile[k0+i][n]; o1[i] = tile[k0+8+i][n]; }
    *(bf16x8*)dst = o0;
    *(bf16x8*)(dst+8) = o1;
  }
}

// ---------------- QKV GEMM + bias; RoPE fused on q/k; V^T written directly ----------------
__global__ __launch_bounds__(256) void k_gemm(const short* __restrict__ A, const short* __restrict__ WT,
                                              const float* __restrict__ biasq, const float* __restrict__ biask,
                                              const float* __restrict__ biasv,
                                              short* __restrict__ oq, short* __restrict__ ok, short* __restrict__ ovt,
                                              const float* __restrict__ cost, const float* __restrict__ sint){
  const int z = blockIdx.z;
  const short* Bw = WT + (size_t)z*E_*E_;
  const float* bias = z==0 ? biasq : (z==1 ? biask : biasv);
  __shared__ short As[128*32];
  __shared__ short Bs[128*32];
  const int t = threadIdx.x, lane = t & 63, wid = t >> 6;
  const int mb = blockIdx.x*128, nb = blockIdx.y*128;
  const int wm = (wid>>1)*64, wn = (wid&1)*64;
  f32x4 acc[4][4] = {};
  for(int kt=0; kt<E_/32; kt++){
    __syncthreads();
    {
      int f0 = t, f1 = t + 256;
      GLD16(A  + (size_t)(mb + (f0>>2))*E_ + kt*32 + (f0&3)*8, &As[f0*8]);
      GLD16(A  + (size_t)(mb + (f1>>2))*E_ + kt*32 + (f1&3)*8, &As[f1*8]);
      GLD16(Bw + (size_t)(nb + (f0>>2))*E_ + kt*32 + (f0&3)*8, &Bs[f0*8]);
      GLD16(Bw + (size_t)(nb + (f1>>2))*E_ + kt*32 + (f1&3)*8, &Bs[f1*8]);
    }
    __syncthreads();
    bf16x8 af[4], bfv[4];
    #pragma unroll
    for(int mf=0; mf<4; mf++)
      af[mf] = *(const bf16x8*)&As[(wm + mf*16 + (lane&15))*32 + (lane>>4)*8];
    #pragma unroll
    for(int nf=0; nf<4; nf++)
      bfv[nf] = *(const bf16x8*)&Bs[(wn + nf*16 + (lane&15))*32 + (lane>>4)*8];
    #pragma unroll
    for(int mf=0; mf<4; mf++)
      #pragma unroll
      for(int nf=0; nf<4; nf++)
        acc[mf][nf] = __builtin_amdgcn_mfma_f32_16x16x32_bf16(af[mf], bfv[nf], acc[mf][nf], 0, 0, 0);
  }
  const int col16 = lane & 15, rg = lane >> 4;
  float bvs[4];
  #pragma unroll
  for(int nf=0; nf<4; nf++) bvs[nf] = bias[nb + wn + nf*16 + col16];
  if(z == 2){
    // direct V^T store: vt[((b*H+h)*D+d)*S + s]; 4 consecutive acc rows = 8B along S
    #pragma unroll
    for(int mf=0; mf<4; mf++){
      int row0 = mb + wm + mf*16 + rg*4;
      int bb2 = row0 >> 11, ss = row0 & (S_-1);
      #pragma unroll
      for(int nf=0; nf<4; nf++){
        int e = nb + wn + nf*16 + col16;
        int hh = e >> 6, dd = e & 63;
        s16x4 w = { (short)f2bf(acc[mf][nf][0]+bvs[nf]), (short)f2bf(acc[mf][nf][1]+bvs[nf]),
                    (short)f2bf(acc[mf][nf][2]+bvs[nf]), (short)f2bf(acc[mf][nf][3]+bvs[nf]) };
        *(s16x4*)(ovt + ((size_t)(bb2*H_+hh)*D_+dd)*S_ + ss) = w;
      }
    }
  } else {
    short* out = (z==0) ? oq : ok;
    // wave col-span nb+wn..+63 = exactly one head; RoPE pairs (d, d+32) = (nf, nf+2)
    const float qs = (z==0) ? (0.125f*L2E) : 1.0f;   // fold score scale + log2e into q
    #pragma unroll
    for(int mf=0; mf<4; mf++)
      #pragma unroll
      for(int r=0; r<4; r++){
        int row = mb + wm + mf*16 + rg*4 + r;
        int srow = row & (S_-1);
        const float* cb = cost + (size_t)srow*32;
        const float* sb = sint + (size_t)srow*32;
        #pragma unroll
        for(int nf=0; nf<2; nf++){
          int d = nf*16 + col16;
          float c = cb[d], sn = sb[d];
          float x0 = acc[mf][nf][r]   + bvs[nf];
          float x1 = acc[mf][nf+2][r] + bvs[nf+2];
          out[(size_t)row*E_ + nb + wn + nf*16 + col16]     = (short)f2bf((x0*c - x1*sn)*qs);
          out[(size_t)row*E_ + nb + wn + (nf+2)*16 + col16] = (short)f2bf((x1*c + x0*sn)*qs);
        }
      }
  }
}

// ---------------- Flash attention, KVBLK=32, split-KV x ns, double-buffered LDS ----------------
// Halved tile (32 keys): LDS 19456B (up to 8 blocks/CU), s-transient 16 regs.
// sp=0 -> f32 partial in d_out; sp>=1 -> f16 partial in its own disjoint buffer.
__global__ __launch_bounds__(256,4) void k_attn(
    const short* __restrict__ qg, const short* __restrict__ kg,
    const short* __restrict__ vtg, const float* __restrict__ maskC,
    float* __restrict__ o0g, _Float16* __restrict__ p1g, _Float16* __restrict__ p2g,
    float* __restrict__ lpart, int ns){
  __shared__ short Ks[2][32*72];   // [buf][key][d] pad-72 (9216B)
  __shared__ short Vs[2][64*40];   // [buf][d][key] pad-40 (10240B)
  // flat grid, XCD-clustered: xcd = flat&7 hosts 4 bh; per-xcd inner = 16 qb * ns
  const int flat = blockIdx.x;
  const unsigned v = (unsigned)(flat >> 3);
  const unsigned per_bh = 16u * (unsigned)ns;
  const int bh = (flat & 7)*4 + (int)(v / per_bh);
  const unsigned inner = v % per_bh;
  const int qb = (int)(inner / (unsigned)ns), sp = (int)(inner % (unsigned)ns);
  const int h = bh & 15, b = bh >> 4;
  const int tid = threadIdx.x, wid = tid>>6, lane = tid&63;
  const int l31 = lane & 31, hl = lane >> 5;
  const int qw = qb*128 + wid*32;
  const int rr = tid>>3, ch = tid&7;        // K staging: key-row rr, d-chunk ch
  const int vr = tid>>2, vc = tid&3;        // V staging: d-row vr, s-chunk vc
  const int kb0 = (sp*64)/ns;
  const int NT  = ((sp+1)*64)/ns - kb0;     // 32-key tiles

  bf16x8 qf[4];
  {
    const short* qp = qg + ((size_t)(b*S_ + qw + l31)*H_ + h)*D_;
    #pragma unroll
    for(int dk=0; dk<4; dk++)
      qf[dk] = *(const bf16x8*)(qp + dk*16 + hl*8);
  }
  f32x16 O0 = {}, O1 = {};
  float l_run = 0.f;
  const float* mrow = maskC + (size_t)b*S_;

  bf16x8 ka, va;
#define LOADT(kb) { \
    ka = *(const bf16x8*)(kg + ((size_t)(b*S_ + (kb)*32 + rr)*H_ + h)*D_ + ch*8); \
    va = *(const bf16x8*)(vtg + ((size_t)(b*H_ + h)*D_ + vr)*S_ + (kb)*32 + vc*8); }
#define WRITET(pp) { \
    *(bf16x8*)&Ks[pp][rr*72 + ch*8] = ka; \
    *(bf16x8*)&Vs[pp][vr*40 + vc*8] = va; }

  LOADT(kb0);
  WRITET(0);
  LOADT(kb0+1);
  asm volatile("s_waitcnt lgkmcnt(0)" ::: "memory");
  __builtin_amdgcn_s_barrier();

  int p = 0;
  for(int tt=0; tt<NT; tt++){
    // ---- QK^T from buf p: lane holds q-col l31, rows = 32 keys (log2 units) ----
    f32x16 s = {};
    __builtin_amdgcn_s_setprio(1);
    #pragma unroll
    for(int dk=0; dk<4; dk++){
      bf16x8 kf = *(const bf16x8*)&Ks[p][(l31)*72 + dk*16 + hl*8];
      s = __builtin_amdgcn_mfma_f32_32x32x16_bf16(kf, qf[dk], s, 0,0,0);
    }
    __builtin_amdgcn_s_setprio(0);
    // + log2-domain mask; reg r=a+4*bb -> key = a + 8*bb + 4*hl
    {
      const float* mt = mrow + (kb0+tt)*32 + hl*4;
      #pragma unroll
      for(int bb=0; bb<4; bb++){
        f32x4 mv = *(const f32x4*)(mt + bb*8);
        #pragma unroll
        for(int a=0; a<4; a++) s[bb*4+a] += mv[a];
      }
    }
    #pragma unroll
    for(int i=0;i<16;i++) s[i] = __builtin_amdgcn_exp2f(s[i]);
    float la=0.f, lb=0.f, lc=0.f, ld=0.f;
    #pragma unroll
    for(int i=0;i<4;i++){
      la += s[i];   lb += s[4+i];  lc += s[8+i];  ld += s[12+i];
    }
    float ls = (la+lb)+(lc+ld);
    ls += __shfl_xor(ls, 32);
    l_run += ls;

    // pack P to bf16 words; c covers keys 8c + 4hl + {0..3}
    unsigned w0a[4], w1a[4];
    #pragma unroll
    for(int c=0;c<4;c++){
      int base = c*4;
      w0a[c] = pk_bf16(s[base+0], s[base+1]);
      w1a[c] = pk_bf16(s[base+2], s[base+3]);
    }

    // ---- stage tile tt+1 into buf p^1 (loads issued a tile ago), issue tt+2 ----
    if(tt+1 < NT){
      WRITET(p^1);
      if(tt+2 < NT) LOADT(kb0+tt+2);
    }

    // ---- PV from buf p (2 k-slices of 16) ----
    __builtin_amdgcn_s_setprio(1);
    #pragma unroll
    for(int ksl=0; ksl<2; ksl++){
      unsigned a0 = w0a[2*ksl], b0 = w0a[2*ksl+1];
      unsigned a1 = w1a[2*ksl], b1 = w1a[2*ksl+1];
      asm("v_permlane32_swap_b32 %0, %1" : "+v"(a0), "+v"(b0));
      asm("v_permlane32_swap_b32 %0, %1" : "+v"(a1), "+v"(b1));
      u32x4 pw = { a0, a1, b0, b1 };
      bf16x8 pf = __builtin_bit_cast(bf16x8, pw);
      bf16x8 vf0 = *(const bf16x8*)&Vs[p][(l31)*40 + ksl*16 + hl*8];
      bf16x8 vf1 = *(const bf16x8*)&Vs[p][(32+l31)*40 + ksl*16 + hl*8];
      O0 = __builtin_amdgcn_mfma_f32_32x32x16_bf16(pf, vf0, O0, 0,0,0);
      O1 = __builtin_amdgcn_mfma_f32_32x32x16_bf16(pf, vf1, O1, 0,0,0);
    }
    __builtin_amdgcn_s_setprio(0);
    asm volatile("s_waitcnt lgkmcnt(0)" ::: "memory");
    __builtin_amdgcn_s_barrier();
    p ^= 1;
  }
#undef LOADT
#undef WRITET

  // raw partial store into DISJOINT buffers; k_comb divides by sum of l
  if(sp == 0){
    #pragma unroll
    for(int bb=0; bb<4; bb++)
      #pragma unroll
      for(int a=0; a<4; a++){
        int qrow = qw + a + 8*bb + 4*hl;
        float* op = o0g + ((size_t)(b*S_ + qrow)*H_ + h)*D_;
        op[l31]      = O0[bb*4+a];
        op[32 + l31] = O1[bb*4+a];
      }
  } else {
    _Float16* pbuf = (sp == 1) ? p1g : p2g;
    #pragma unroll
    for(int bb=0; bb<4; bb++)
      #pragma unroll
      for(int a=0; a<4; a++){
        int qrow = qw + a + 8*bb + 4*hl;
        _Float16* op = pbuf + ((size_t)(b*S_ + qrow)*H_ + h)*D_;
        op[l31]      = (_Float16)O0[bb*4+a];
        op[32 + l31] = (_Float16)O1[bb*4+a];
      }
  }
  if(lane < 32)
    lpart[(size_t)sp*NH_ + (size_t)(b*S_ + qw + l31)*H_ + h] = l_run;
}

// ---------------- combine: out = (P0 + P1 [+ P2]) / (l0 + l1 [+ l2]) ----------------
__global__ __launch_bounds__(256) void k_comb(float* __restrict__ out, const _Float16* __restrict__ p1,
                                              const _Float16* __restrict__ p2,
                                              const float* __restrict__ lpart, int ns){
  int i = blockIdx.x*256 + threadIdx.x;
  int idx = i*4;
  int lidx = idx >> 6;                       // (b*S+q)*H + h
  float l = lpart[lidx] + lpart[NH_ + lidx];
  if(ns > 2) l += lpart[2*NH_ + lidx];
  float linv = 1.f / l;
  f32x4 a = *(f32x4*)(out + idx);
  f16x4 q1 = *(const f16x4*)(p1 + idx);
  f32x4 r;
  #pragma unroll
  for(int j=0;j<4;j++) r[j] = a[j] + (float)q1[j];
  if(ns > 2){
    f16x4 q2 = *(const f16x4*)(p2 + idx);
    #pragma unroll
    for(int j=0;j<4;j++) r[j] += (float)q2[j];
  }
  #pragma unroll
  for(int j=0;j<4;j++) r[j] *= linv;
  *(f32x4*)(out + idx) = r;
}

extern "C" void kernel_launch(void* const* d_in, const int* in_sizes, int n_in,
                              void* d_out, int out_size, void* d_ws, size_t ws_size,
                              hipStream_t stream){
  (void)in_sizes; (void)n_in; (void)out_size;
  const float* x    = (const float*)d_in[0];
  const float* mask = (const float*)d_in[1];
  const float* Wq   = (const float*)d_in[2];
  const float* bq   = (const float*)d_in[3];
  const float* Wk   = (const float*)d_in[4];
  const float* bk   = (const float*)d_in[5];
  const float* Wv   = (const float*)d_in[6];
  const float* bv   = (const float*)d_in[7];
  float* out = (float*)d_out;
  char* ws = (char*)d_ws;
  // ws map: [0,40M) proven; p2 @ [40M,48M) used only if ws_size >= 48M.
  float* cost  = (float*)(ws);                   // 256K
  float* sint  = (float*)(ws + (256u<<10));      // 256K
  float* maskC = (float*)(ws + (512u<<10));      // 16K
  float* lpart = (float*)(ws + (768u<<10));      // 768K (3 x 4096x16 f32)
  short* xb    = (short*)(ws + (2u<<20));        // 8M  x bf16 (aliased by f16 partial p1)
  short* wt    = (short*)(ws + (10u<<20));       // 6M  W^T bf16
  short* qb    = (short*)(ws + (16u<<20));       // 8M  q bf16
  short* kb    = (short*)(ws + (24u<<20));       // 8M  k bf16
  short* vtb   = (short*)(ws + (32u<<20));       // 8M  V^T bf16
  _Float16* p1 = (_Float16*)xb;                  // alias: xb dead after k_gemm
  _Float16* p2 = (_Float16*)(ws + (40u<<20));    // only valid if ws >= 48M

  const int ns = (ws_size >= (size_t)(48u<<20)) ? 3 : 2;   // split count (runtime, deterministic)

  k_cvt<<<dim3(4096), dim3(256), 0, stream>>>(x, xb, mask, cost, sint, maskC);
  k_wt<<<dim3(16,16,3), dim3(256), 0, stream>>>(Wq, Wk, Wv, wt);
  k_gemm<<<dim3(32,8,3), dim3(256), 0, stream>>>(xb, wt, bq, bk, bv, qb, kb, vtb, cost, sint);
  k_attn<<<dim3(512*ns), dim3(256), 0, stream>>>(qb, kb, vtb, maskC, out, p1, p2, lpart, ns);
  k_comb<<<dim3(4096), dim3(256), 0, stream>>>(out, p1, p2, lpart, ns);
}